// Round 11
// baseline (314.181 us; speedup 1.0000x reference)
//
#include <hip/hip_runtime.h>
#include <stdint.h>

#define HW 4096
#define NTOK 32768
#define KCB 8192
#define YSPLIT 8
#define KCOV (KCB / YSPLIT)      // 1024 codes per block
#define NCHUNK (KCOV / 64)       // 16 chunks of 64 codes
#define FIN_BLOCKS 512           // finish grid; 2/CU -> all co-resident
// margin in d' units: split-bf16 + fp32-accum error (0.01, empirically safe
// R3-R10) + two-sided fixed-point truncation 2/1024
#define MARGIN 0.0119628906f

typedef __bf16 bf16x8 __attribute__((ext_vector_type(8)));
typedef float f32x16 __attribute__((ext_vector_type(16)));
typedef unsigned int uint;
typedef unsigned short u16;
typedef unsigned long long u64;

static __device__ inline u16 f2bf(float f) {
    uint u = __float_as_uint(f);
    return (u16)((u + 0x7FFFu + ((u >> 16) & 1u)) >> 16);   // RNE
}
static __device__ inline float bf2f(u16 h) {
    return __uint_as_float(((uint)h) << 16);
}
static __device__ inline uint fsort(float f) {
    uint u = __float_as_uint(f);
    return u ^ ((uint)((int)u >> 31) | 0x80000000u);
}
static __device__ inline uint umin2(uint a, uint b) { return a < b ? a : b; }
static __device__ inline uint umax2(uint a, uint b) { return a > b ? a : b; }
static __device__ inline uint umed3(uint a, uint b, uint c) {
    return umax2(umin2(a, b), umin2(umax2(a, b), c));
}

// software grid barrier: all FIN_BLOCKS blocks must be co-resident (2/CU).
// Only lane 0 spins; cross-block data goes through device-scope atomics.
static __device__ inline void grid_barrier(int* cnt, int* rel) {
    __syncthreads();
    if (threadIdx.x == 0) {
        __threadfence();
        int old = atomicAdd(cnt, 1);
        if (old == FIN_BLOCKS - 1) {
            atomicExch(rel, 1);
        } else {
            while (atomicAdd(rel, 0) == 0) __builtin_amdgcn_s_sleep(8);
        }
        __threadfence();
    }
    __syncthreads();
}

// ---------------------------------------------------------------------------
// prep: fused preconv (blocks 0..511) + embprep (blocks 512..767). R10 proven.
// Also zeroes loss accumulator, flag counter, and the 4 barrier words.
// ---------------------------------------------------------------------------
__global__ __launch_bounds__(256) void prep_kernel(
    const float* __restrict__ z, const float* __restrict__ pre_w,
    const float* __restrict__ pre_b, const float* __restrict__ emb,
    u16* __restrict__ zq, u16* __restrict__ embq,
    float* __restrict__ ee, float* __restrict__ eebs,
    float* __restrict__ loss_out, int* __restrict__ flagcnt,
    int* __restrict__ barw)
{
    __shared__ __attribute__((aligned(16))) float wt[64 * 64];
    __shared__ __attribute__((aligned(16))) float zt[64 * 64];
    __shared__ float bls[64];
    const int t  = threadIdx.x;
    const int bx = blockIdx.x;

    if (bx >= 512) {
        const int k   = (bx - 512) * 32 + (t >> 3);
        const int sub = t & 7;
        const float4* er = (const float4*)(emb + (size_t)k * 64 + sub * 8);
        float4 v0 = er[0], v1 = er[1];

        float s = v0.x*v0.x + v0.y*v0.y + v0.z*v0.z + v0.w*v0.w
                + v1.x*v1.x + v1.y*v1.y + v1.z*v1.z + v1.w*v1.w;
        s += __shfl_xor(s, 1, 64);
        s += __shfl_xor(s, 2, 64);
        s += __shfl_xor(s, 4, 64);
        if (sub == 0) { ee[k] = s; eebs[k] = 1024.f * (256.f + s); }

        float vals[8] = {-64.f*v0.x, -64.f*v0.y, -64.f*v0.z, -64.f*v0.w,
                         -64.f*v1.x, -64.f*v1.y, -64.f*v1.z, -64.f*v1.w};
        u16 hb[8], lb[8];
        #pragma unroll
        for (int c = 0; c < 8; ++c) {
            hb[c] = f2bf(vals[c]);
            lb[c] = f2bf(vals[c] - bf2f(hb[c]));
        }
        uint4 uh, ul;
        uh.x = (uint)hb[0] | ((uint)hb[1] << 16);
        uh.y = (uint)hb[2] | ((uint)hb[3] << 16);
        uh.z = (uint)hb[4] | ((uint)hb[5] << 16);
        uh.w = (uint)hb[6] | ((uint)hb[7] << 16);
        ul.x = (uint)lb[0] | ((uint)lb[1] << 16);
        ul.y = (uint)lb[2] | ((uint)lb[3] << 16);
        ul.z = (uint)lb[4] | ((uint)lb[5] << 16);
        ul.w = (uint)lb[6] | ((uint)lb[7] << 16);

        const int sw = k & 7;
        uint4* out = (uint4*)(embq + (size_t)k * 128);
        out[sub ^ sw]       = uh;
        out[(8 + sub) ^ sw] = ul;
        if (bx == 512 && t == 0) {
            loss_out[0] = 0.f;
            atomicExch(flagcnt, 0);
            atomicExch(&barw[0], 0); atomicExch(&barw[1], 0);
            atomicExch(&barw[2], 0); atomicExch(&barw[3], 0);
        }
        return;
    }

    const int tok0 = bx * 64;
    const int b    = tok0 >> 12;
    const int hw0  = tok0 & 4095;

    for (int i = t; i < 64 * 64; i += 256) {
        int o = i >> 6, c = i & 63;
        wt[c * 64 + o] = pre_w[i];
    }
    if (t < 64) bls[t] = pre_b[t];
    {
        const int tl = t & 63;
        #pragma unroll
        for (int rr = 0; rr < 16; ++rr) {
            const int c = (t >> 6) + rr * 4;
            zt[c * 64 + tl] = z[(size_t)b * (64 * HW) + (size_t)c * HW + hw0 + tl];
        }
    }
    __syncthreads();

    const int tok = t >> 2;
    const int og  = t & 3;
    const int n   = tok0 + tok;

    float acc[16];
    #pragma unroll
    for (int j = 0; j < 16; ++j) acc[j] = 0.f;

    for (int c = 0; c < 64; ++c) {
        const float zv = zt[c * 64 + tok];
        #pragma unroll
        for (int g = 0; g < 4; ++g) {
            float4 w4 = *(const float4*)(wt + c * 64 + og * 16 + g * 4);
            acc[g*4+0] = fmaf(zv, w4.x, acc[g*4+0]);
            acc[g*4+1] = fmaf(zv, w4.y, acc[g*4+1]);
            acc[g*4+2] = fmaf(zv, w4.z, acc[g*4+2]);
            acc[g*4+3] = fmaf(zv, w4.w, acc[g*4+3]);
        }
    }
    #pragma unroll
    for (int j = 0; j < 16; ++j) acc[j] = 32.f * (acc[j] + bls[og * 16 + j]);

    uint uh[8], ul[8];
    #pragma unroll
    for (int j = 0; j < 8; ++j) {
        float v0 = acc[2*j], v1 = acc[2*j+1];
        u16 h0 = f2bf(v0), h1 = f2bf(v1);
        u16 l0 = f2bf(v0 - bf2f(h0)), l1 = f2bf(v1 - bf2f(h1));
        uh[j] = (uint)h0 | ((uint)h1 << 16);
        ul[j] = (uint)l0 | ((uint)l1 << 16);
    }
    uint4* zh = (uint4*)(zq + (size_t)n * 128 + og * 16);
    uint4* zl = (uint4*)(zq + (size_t)n * 128 + 64 + og * 16);
    zh[0] = *(uint4*)&uh[0]; zh[1] = *(uint4*)&uh[4];
    zl[0] = *(uint4*)&ul[0]; zl[1] = *(uint4*)&ul[4];
}

// ---------------------------------------------------------------------------
// dist: UNCHANGED from R8/R10 (split-bf16 MFMA + fixed-point u32 top-2).
// ---------------------------------------------------------------------------
__global__ __launch_bounds__(256, 4) void dist_kernel(
    const u16* __restrict__ zq, const u16* __restrict__ embq,
    const float* __restrict__ eebs, uint* __restrict__ halfbb,
    uint* __restrict__ halfss)
{
    __shared__ __attribute__((aligned(16))) char smem[32768];
    __shared__ uint gbk[128];

    const int t    = threadIdx.x;
    const int w    = t >> 6;
    const int l    = t & 63;
    const int col  = l & 31;
    const int half = l >> 5;
    const int tok0 = blockIdx.x * 128;
    const int y    = blockIdx.y;
    const int kbase = y * KCOV;

    bf16x8 ah[4], al[4];
    {
        const u16* zrow = zq + (size_t)(tok0 + w * 32 + col) * 128;
        #pragma unroll
        for (int s = 0; s < 4; ++s) {
            ah[s] = *(const bf16x8*)(zrow + s*16 + half*8);
            al[s] = *(const bf16x8*)(zrow + 64 + s*16 + half*8);
        }
    }

    const int sw = col & 7;
    int boh[4][2], bol[4][2];
    #pragma unroll
    for (int s = 0; s < 4; ++s)
        #pragma unroll
        for (int ct = 0; ct < 2; ++ct) {
            const int nl = ct * 32 + col;
            boh[s][ct] = nl * 256 + (((s*2 + half) ^ sw) << 4);
            bol[s][ct] = nl * 256 + (((8 + s*2 + half) ^ sw) << 4);
        }

    uint bb[16], ss[16];
    #pragma unroll
    for (int r = 0; r < 16; ++r) { bb[r] = 0xFFFFFFFFu; ss[r] = 0xFFFFFFFFu; }

    float e0 = eebs[kbase + col];
    float e1 = eebs[kbase + 32 + col];

    {
        const char* g = (const char*)embq + (size_t)kbase * 256;
        #pragma unroll
        for (int i = 0; i < 4; ++i) {
            int off = i * 4096 + t * 16;
            __builtin_amdgcn_global_load_lds(
                (const __attribute__((address_space(1))) void*)(g + off),
                (__attribute__((address_space(3))) void*)(smem + off), 16, 0, 0);
        }
    }

    for (int kt = 0; kt < NCHUNK; ++kt) {
        __syncthreads();
        if (kt + 1 < NCHUNK) {
            const char* g = (const char*)embq + (size_t)kbase * 256 + (size_t)(kt + 1) * 16384;
            char* ld = smem + ((kt + 1) & 1) * 16384;
            #pragma unroll
            for (int i = 0; i < 4; ++i) {
                int off = i * 4096 + t * 16;
                __builtin_amdgcn_global_load_lds(
                    (const __attribute__((address_space(1))) void*)(g + off),
                    (__attribute__((address_space(3))) void*)(ld + off), 16, 0, 0);
            }
        }
        const char* buf = smem + (kt & 1) * 16384;

        float e0n = 0.f, e1n = 0.f;
        if (kt + 1 < NCHUNK) {
            e0n = eebs[kbase + (kt+1)*64 + col];
            e1n = eebs[kbase + (kt+1)*64 + 32 + col];
        }

        f32x16 a0, a1;
        #pragma unroll
        for (int r = 0; r < 16; ++r) { a0[r] = e0; a1[r] = e1; }

        #pragma unroll
        for (int s = 0; s < 4; ++s) {
            bf16x8 bh0 = *(const bf16x8*)(buf + boh[s][0]);
            bf16x8 bh1 = *(const bf16x8*)(buf + boh[s][1]);
            bf16x8 bl0 = *(const bf16x8*)(buf + bol[s][0]);
            bf16x8 bl1 = *(const bf16x8*)(buf + bol[s][1]);
            a0 = __builtin_amdgcn_mfma_f32_32x32x16_bf16(ah[s], bh0, a0, 0, 0, 0);
            a1 = __builtin_amdgcn_mfma_f32_32x32x16_bf16(ah[s], bh1, a1, 0, 0, 0);
            a0 = __builtin_amdgcn_mfma_f32_32x32x16_bf16(ah[s], bl0, a0, 0, 0, 0);
            a1 = __builtin_amdgcn_mfma_f32_32x32x16_bf16(ah[s], bl1, a1, 0, 0, 0);
            a0 = __builtin_amdgcn_mfma_f32_32x32x16_bf16(al[s], bh0, a0, 0, 0, 0);
            a1 = __builtin_amdgcn_mfma_f32_32x32x16_bf16(al[s], bh1, a1, 0, 0, 0);
        }

        const uint i0 = (uint)(kt * 64 + col);
        const uint i1 = i0 + 32;
        #pragma unroll
        for (int r = 0; r < 16; ++r) {
            const uint p0 = (((uint)a0[r]) << 10) + i0;
            const uint p1 = (((uint)a1[r]) << 10) + i1;
            ss[r] = umin2(ss[r], umed3(bb[r], p0, p1));
            bb[r] = umin2(umin2(bb[r], p0), p1);
        }
        e0 = e0n; e1 = e1n;
    }

    __syncthreads();
    uint* keyt = (uint*)smem;    // [128 tokens][32 slots] u32 = 16 KB
    #pragma unroll
    for (int r = 0; r < 16; ++r) {
        const int tl = w*32 + (r & 3) + 8*(r >> 2) + 4*half;
        keyt[tl * 32 + col] = bb[r];
    }
    __syncthreads();
    if (t < 128) {
        uint gb = keyt[t * 32 + (t & 31)];
        #pragma unroll 4
        for (int j = 1; j < 32; ++j)
            gb = umin2(gb, keyt[t * 32 + ((j + t) & 31)]);
        gbk[t] = gb;
    }
    __syncthreads();
    #pragma unroll
    for (int r = 0; r < 16; ++r) {
        const int tl = w*32 + (r & 3) + 8*(r >> 2) + 4*half;
        const uint mykey = bb[r];
        keyt[tl * 32 + col] = (mykey == gbk[tl]) ? ss[r] : mykey;
    }
    __syncthreads();
    if (t < 128) {
        uint sv = keyt[t * 32 + (t & 31)];
        #pragma unroll 4
        for (int j = 1; j < 32; ++j)
            sv = umin2(sv, keyt[t * 32 + ((j + t) & 31)]);
        halfbb[(size_t)y * NTOK + tok0 + t] = gbk[t];
        halfss[(size_t)y * NTOK + tok0 + t] = sv;
    }
}

// ---------------------------------------------------------------------------
// finish: fused merge + parallel cleanup + gather, with software grid
// barriers. Grid = 512 blocks x 256 (2 blocks/CU -> all co-resident; LDS
// 33 KB). Phase A: merge 64 tokens/block (indices stay in LDS; flagged ->
// global flaglist via atomics). Barrier. Phase B: R8's 32-slice exact rescan
// grid-strided over ALL 512 blocks (no per-block straggler). Barrier.
// Phase C: resolve flagged indices from bestkeyB, then R10 gather verbatim.
// All cross-block data moves through device-scope atomics.
// ---------------------------------------------------------------------------
__global__ __launch_bounds__(256, 2) void finish_kernel(
    const float* __restrict__ emb, const float* __restrict__ ee,
    const uint* __restrict__ halfbb, const uint* __restrict__ halfss,
    const u16* __restrict__ zq, const float* __restrict__ post_w,
    const float* __restrict__ post_b, float* __restrict__ out,
    float* __restrict__ loss_out, u64* __restrict__ bestkeyB,
    int* __restrict__ flagcnt, int* __restrict__ flaglist,
    int* __restrict__ barw)
{
    __shared__ __attribute__((aligned(16))) float wt[64 * 64];  // wt[c*64+o]
    __shared__ __attribute__((aligned(16))) float qt[64 * 64];  // qt[c*64+tok] / zf overlay
    __shared__ float bls[64];
    __shared__ int idxs[64];
    __shared__ float red[4];
    __shared__ u64 skey;
    const int t = threadIdx.x;
    const int tok0 = blockIdx.x * 64;
    const int b    = tok0 >> 12;
    const int hw0  = tok0 & 4095;
    float* zf = qt;   // phase-B overlay (qt unused until phase C)

    // ---- phase A: merge + wt staging ----
    for (int i = t; i < 64 * 64; i += 256) {
        int o = i >> 6, c = i & 63;
        wt[c * 64 + o] = post_w[i];
    }
    if (t < 64) {
        bls[t] = post_b[t];
        const int n = tok0 + t;
        uint m1 = 0xFFFFFFFFu, m2 = 0xFFFFFFFFu, smin = 0xFFFFFFFFu;
        int ywin = 0;
        #pragma unroll
        for (int y = 0; y < YSPLIT; ++y) {
            const uint kb = halfbb[(size_t)y * NTOK + n];
            if (kb < m1) { m2 = m1; m1 = kb; ywin = y; }
            else if (kb < m2) m2 = kb;
            smin = umin2(smin, halfss[(size_t)y * NTOK + n]);
        }
        const uint bv_u = m1 >> 10;
        const uint sv_u = umin2(m2, smin) >> 10;
        const float gap = (float)(sv_u - bv_u) * 9.765625e-4f;   // /1024
        const bool flag = (gap < MARGIN) | (bv_u < (128u << 10));
        if (flag) {
            idxs[t] = -1;
            atomicExch(&bestkeyB[n], ~0ull);
            int pos = atomicAdd(flagcnt, 1);
            atomicExch(&flaglist[pos], n);
        } else {
            idxs[t] = (int)((uint)(ywin * 1024) + (m1 & 1023u));
        }
    }

    grid_barrier(&barw[0], &barw[1]);

    // ---- phase B: parallel exact rescan (R8 cleanup, stride 512) ----
    {
        const int fcnt = atomicAdd(flagcnt, 0);
        for (int job = blockIdx.x; job < fcnt * 32; job += FIN_BLOCKS) {
            const int fi    = job >> 5;
            const int slice = job & 31;
            const int tok   = atomicAdd(&flaglist[fi], 0);
            if (t == 0) skey = ~0ull;
            if (t < 64) {
                const u16* zr = zq + (size_t)tok * 128;
                zf[t] = (bf2f(zr[t]) + bf2f(zr[64 + t])) * 0.03125f;  // zq = 32*ze
            }
            __syncthreads();

            const int k = slice * 256 + t;
            const float4* er = (const float4*)(emb + (size_t)k * 64);
            float d = 0.f;
            #pragma unroll
            for (int jj = 0; jj < 16; ++jj) {
                float4 e = er[jj];
                float4 zv = *(const float4*)&zf[4*jj];
                d = fmaf(e.x, zv.x, fmaf(e.y, zv.y, fmaf(e.z, zv.z, fmaf(e.w, zv.w, d))));
            }
            float dd = fmaf(-2.f, d, ee[k]);
            u64 key = ((u64)fsort(dd) << 32) | (uint)k;
            #pragma unroll
            for (int off = 32; off > 0; off >>= 1) {
                u64 o = __shfl_down(key, off, 64);
                key = (o < key) ? o : key;
            }
            if ((t & 63) == 0) atomicMin(&skey, key);
            __syncthreads();
            if (t == 0) atomicMin(&bestkeyB[tok], skey);
            __syncthreads();
        }
    }

    grid_barrier(&barw[2], &barw[3]);

    // ---- phase C: resolve flagged indices, then gather (R10 verbatim) ----
    if (t < 64 && idxs[t] < 0)
        idxs[t] = (int)(atomicAdd(&bestkeyB[tok0 + t], 0ull) & 0xFFFFFFFFull);
    __syncthreads();

    const int tok = t >> 2;
    const int og  = t & 3;
    const int n   = tok0 + tok;

    {
        const float4* qr = (const float4*)(emb + (size_t)idxs[tok] * 64);
        #pragma unroll
        for (int p = 0; p < 4; ++p) {
            const int c0 = og * 16 + p * 4;
            float4 v = qr[c0 >> 2];
            qt[(c0+0) * 64 + tok] = v.x;
            qt[(c0+1) * 64 + tok] = v.y;
            qt[(c0+2) * 64 + tok] = v.z;
            qt[(c0+3) * 64 + tok] = v.w;
        }
    }
    __syncthreads();

    float lsum = 0.f;
    {
        const uint4* zh = (const uint4*)(zq + (size_t)n * 128 + og * 16);
        const uint4* zl = (const uint4*)(zq + (size_t)n * 128 + 64 + og * 16);
        #pragma unroll
        for (int h = 0; h < 2; ++h) {
            uint4 uh = zh[h], ul = zl[h];
            const uint uhv[4] = {uh.x, uh.y, uh.z, uh.w};
            const uint ulv[4] = {ul.x, ul.y, ul.z, ul.w};
            #pragma unroll
            for (int p = 0; p < 4; ++p) {
                const int c = og * 16 + h * 8 + p * 2;
                float z0 = (bf2f((u16)(uhv[p] & 0xFFFF)) + bf2f((u16)(ulv[p] & 0xFFFF))) * 0.03125f;
                float z1 = (bf2f((u16)(uhv[p] >> 16))    + bf2f((u16)(ulv[p] >> 16)))    * 0.03125f;
                float d0 = z0 - qt[c * 64 + tok];
                float d1 = z1 - qt[(c + 1) * 64 + tok];
                lsum += d0 * d0 + d1 * d1;
            }
        }
    }

    {
        const int w    = t >> 6;
        const int lane = t & 63;
        float acc[16];
        #pragma unroll
        for (int j = 0; j < 16; ++j) acc[j] = 0.f;

        for (int c = 0; c < 64; ++c) {
            const float qv = qt[c * 64 + lane];
            #pragma unroll
            for (int g = 0; g < 4; ++g) {
                float4 w4 = *(const float4*)(wt + c * 64 + w * 16 + g * 4);  // wave-uniform
                acc[g*4+0] = fmaf(qv, w4.x, acc[g*4+0]);
                acc[g*4+1] = fmaf(qv, w4.y, acc[g*4+1]);
                acc[g*4+2] = fmaf(qv, w4.z, acc[g*4+2]);
                acc[g*4+3] = fmaf(qv, w4.w, acc[g*4+3]);
            }
        }
        float* op = out + (size_t)b * (64 * HW) + hw0 + lane;
        #pragma unroll
        for (int j = 0; j < 16; ++j)
            op[(size_t)(w * 16 + j) * HW] = acc[j] + bls[w * 16 + j];  // 256B coalesced
    }

    #pragma unroll
    for (int off = 32; off > 0; off >>= 1) lsum += __shfl_down(lsum, off, 64);
    if ((t & 63) == 0) red[t >> 6] = lsum;
    __syncthreads();
    if (t == 0) {
        const float tot = red[0] + red[1] + red[2] + red[3];
        atomicAdd(loss_out, tot * (1.25f / 2097152.f));   // 1.25/(NTOK*64)
    }
}

// ---------------------------------------------------------------------------
extern "C" void kernel_launch(void* const* d_in, const int* in_sizes, int n_in,
                              void* d_out, int out_size, void* d_ws, size_t ws_size,
                              hipStream_t stream)
{
    const float* z      = (const float*)d_in[0];
    const float* pre_w  = (const float*)d_in[1];
    const float* pre_b  = (const float*)d_in[2];
    const float* emb    = (const float*)d_in[3];
    const float* post_w = (const float*)d_in[4];
    const float* post_b = (const float*)d_in[5];
    float* outp = (float*)d_out;
    float* loss_out = outp + (size_t)NTOK * 64;

    u16*   zq       = (u16*)d_ws;                          // 8 MB
    float* ee       = (float*)(zq + (size_t)NTOK * 128);   // 32 KB
    float* eebs     = ee + KCB;                            // 32 KB
    u16*   embq     = (u16*)(eebs + KCB);                  // 2 MB
    u64*   bestkeyB = (u64*)(embq + (size_t)KCB * 128);    // 256 KB (8B-aligned)
    int*   flagcnt  = (int*)(bestkeyB + NTOK);             // 4 B
    int*   barw     = flagcnt + 1;                         // 4 ints (barriers)
    int*   flaglist = barw + 4;                            // 128 KB
    uint*  halfbb   = (uint*)(flaglist + NTOK);            // 1 MB
    uint*  halfss   = halfbb + (size_t)YSPLIT * NTOK;      // 1 MB

    prep_kernel<<<768, 256, 0, stream>>>(z, pre_w, pre_b, emb, zq, embq, ee, eebs,
                                         loss_out, flagcnt, barw);
    dist_kernel<<<dim3(NTOK / 128, YSPLIT), 256, 0, stream>>>(zq, embq, eebs, halfbb, halfss);
    finish_kernel<<<FIN_BLOCKS, 256, 0, stream>>>(emb, ee, halfbb, halfss, zq,
                                                  post_w, post_b, outp, loss_out,
                                                  bestkeyB, flagcnt, flaglist, barw);
}

// Round 12
// 230.179 us; speedup vs baseline: 1.3649x; 1.3649x over previous
//
#include <hip/hip_runtime.h>
#include <stdint.h>

#define HW 4096
#define NTOK 32768
#define KCB 8192
#define YSPLIT 8
#define KCOV (KCB / YSPLIT)      // 1024 codes per block
#define NCHUNK (KCOV / 64)       // 16 chunks of 64 codes
// margin in d' units: split-bf16 + fp32-accum error (0.01, empirically safe
// R3-R10) + two-sided fixed-point truncation 2/1024
#define MARGIN 0.0119628906f

typedef __bf16 bf16x8 __attribute__((ext_vector_type(8)));
typedef float f32x16 __attribute__((ext_vector_type(16)));
typedef unsigned int uint;
typedef unsigned short u16;
typedef unsigned long long u64;

static __device__ inline u16 f2bf(float f) {
    uint u = __float_as_uint(f);
    return (u16)((u + 0x7FFFu + ((u >> 16) & 1u)) >> 16);   // RNE
}
static __device__ inline float bf2f(u16 h) {
    return __uint_as_float(((uint)h) << 16);
}
static __device__ inline uint fsort(float f) {
    uint u = __float_as_uint(f);
    return u ^ ((uint)((int)u >> 31) | 0x80000000u);
}
static __device__ inline uint umin2(uint a, uint b) { return a < b ? a : b; }
static __device__ inline uint umax2(uint a, uint b) { return a > b ? a : b; }
static __device__ inline uint umed3(uint a, uint b, uint c) {
    return umax2(umin2(a, b), umin2(umax2(a, b), c));
}

// ---------------------------------------------------------------------------
// prep: three sections by blockIdx.
//  [0,512):   preconv: ze = z @ pre_w^T + pre_b -> zq = hi/lo bf16 of 32*ze
//  [512,768): embprep: ee, eebs, embq (-64*e hi/lo, swizzled)
//  [768,896): embW: embWb[k] = emb[k] @ post_w^T + post_b  (the post-conv of
//             every CODE, precomputed once -> finish becomes a row copy)
// ---------------------------------------------------------------------------
__global__ __launch_bounds__(256) void prep_kernel(
    const float* __restrict__ z, const float* __restrict__ pre_w,
    const float* __restrict__ pre_b, const float* __restrict__ emb,
    const float* __restrict__ post_w, const float* __restrict__ post_b,
    u16* __restrict__ zq, u16* __restrict__ embq,
    float* __restrict__ ee, float* __restrict__ eebs,
    float* __restrict__ embWb, float* __restrict__ loss_out,
    int* __restrict__ flagcnt)
{
    __shared__ __attribute__((aligned(16))) float wt[64 * 64];
    __shared__ __attribute__((aligned(16))) float zt[64 * 64];
    __shared__ float bls[64];
    const int t  = threadIdx.x;
    const int bx = blockIdx.x;

    if (bx >= 768) {
        // ---------------- embW: post-conv of all codes ----------------
        const int k0  = (bx - 768) * 64;
        const int tok = t >> 2;      // local code 0..15 per quad.. (t>>2: 0..63)
        const int og  = t & 3;

        for (int i = t; i < 64 * 64; i += 256) {
            int o = i >> 6, c = i & 63;
            wt[c * 64 + o] = post_w[i];
        }
        if (t < 64) bls[t] = post_b[t];
        // stage emb rows c-major: zt[c][code]
        {
            const float4* qr = (const float4*)(emb + (size_t)(k0 + tok) * 64);
            #pragma unroll
            for (int p = 0; p < 4; ++p) {
                const int c0 = og * 16 + p * 4;
                float4 v = qr[c0 >> 2];
                zt[(c0+0) * 64 + tok] = v.x;
                zt[(c0+1) * 64 + tok] = v.y;
                zt[(c0+2) * 64 + tok] = v.z;
                zt[(c0+3) * 64 + tok] = v.w;
            }
        }
        __syncthreads();

        // compute: wave w -> channels w*16..+15, lane = local code
        const int w    = t >> 6;
        const int lane = t & 63;
        float acc[16];
        #pragma unroll
        for (int j = 0; j < 16; ++j) acc[j] = 0.f;
        for (int c = 0; c < 64; ++c) {
            const float qv = zt[c * 64 + lane];
            #pragma unroll
            for (int g = 0; g < 4; ++g) {
                float4 w4 = *(const float4*)(wt + c * 64 + w * 16 + g * 4);
                acc[g*4+0] = fmaf(qv, w4.x, acc[g*4+0]);
                acc[g*4+1] = fmaf(qv, w4.y, acc[g*4+1]);
                acc[g*4+2] = fmaf(qv, w4.z, acc[g*4+2]);
                acc[g*4+3] = fmaf(qv, w4.w, acc[g*4+3]);
            }
        }
        __syncthreads();   // zt fully consumed
        #pragma unroll
        for (int j = 0; j < 16; ++j)
            zt[(w * 16 + j) * 64 + lane] = acc[j] + bls[w * 16 + j];
        __syncthreads();
        // write rows: thread (tok,og) -> embWb[k0+tok][og*16..+15]
        {
            float4* orow = (float4*)(embWb + (size_t)(k0 + tok) * 64 + og * 16);
            #pragma unroll
            for (int p = 0; p < 4; ++p) {
                const int c0 = og * 16 + p * 4;
                float4 v;
                v.x = zt[(c0+0) * 64 + tok];
                v.y = zt[(c0+1) * 64 + tok];
                v.z = zt[(c0+2) * 64 + tok];
                v.w = zt[(c0+3) * 64 + tok];
                orow[p] = v;
            }
        }
        return;
    }

    if (bx >= 512) {
        // ---------------- embprep ----------------
        const int k   = (bx - 512) * 32 + (t >> 3);
        const int sub = t & 7;
        const float4* er = (const float4*)(emb + (size_t)k * 64 + sub * 8);
        float4 v0 = er[0], v1 = er[1];

        float s = v0.x*v0.x + v0.y*v0.y + v0.z*v0.z + v0.w*v0.w
                + v1.x*v1.x + v1.y*v1.y + v1.z*v1.z + v1.w*v1.w;
        s += __shfl_xor(s, 1, 64);
        s += __shfl_xor(s, 2, 64);
        s += __shfl_xor(s, 4, 64);
        if (sub == 0) { ee[k] = s; eebs[k] = 1024.f * (256.f + s); }

        float vals[8] = {-64.f*v0.x, -64.f*v0.y, -64.f*v0.z, -64.f*v0.w,
                         -64.f*v1.x, -64.f*v1.y, -64.f*v1.z, -64.f*v1.w};
        u16 hb[8], lb[8];
        #pragma unroll
        for (int c = 0; c < 8; ++c) {
            hb[c] = f2bf(vals[c]);
            lb[c] = f2bf(vals[c] - bf2f(hb[c]));
        }
        uint4 uh, ul;
        uh.x = (uint)hb[0] | ((uint)hb[1] << 16);
        uh.y = (uint)hb[2] | ((uint)hb[3] << 16);
        uh.z = (uint)hb[4] | ((uint)hb[5] << 16);
        uh.w = (uint)hb[6] | ((uint)hb[7] << 16);
        ul.x = (uint)lb[0] | ((uint)lb[1] << 16);
        ul.y = (uint)lb[2] | ((uint)lb[3] << 16);
        ul.z = (uint)lb[4] | ((uint)lb[5] << 16);
        ul.w = (uint)lb[6] | ((uint)lb[7] << 16);

        const int sw = k & 7;
        uint4* out = (uint4*)(embq + (size_t)k * 128);
        out[sub ^ sw]       = uh;
        out[(8 + sub) ^ sw] = ul;
        if (bx == 512 && t == 0) { loss_out[0] = 0.f; *flagcnt = 0; }
        return;
    }

    // ---------------- preconv ----------------
    const int tok0 = bx * 64;
    const int b    = tok0 >> 12;
    const int hw0  = tok0 & 4095;

    for (int i = t; i < 64 * 64; i += 256) {
        int o = i >> 6, c = i & 63;
        wt[c * 64 + o] = pre_w[i];
    }
    if (t < 64) bls[t] = pre_b[t];
    {
        const int tl = t & 63;
        #pragma unroll
        for (int rr = 0; rr < 16; ++rr) {
            const int c = (t >> 6) + rr * 4;
            zt[c * 64 + tl] = z[(size_t)b * (64 * HW) + (size_t)c * HW + hw0 + tl];
        }
    }
    __syncthreads();

    const int tok = t >> 2;
    const int og  = t & 3;
    const int n   = tok0 + tok;

    float acc[16];
    #pragma unroll
    for (int j = 0; j < 16; ++j) acc[j] = 0.f;

    for (int c = 0; c < 64; ++c) {
        const float zv = zt[c * 64 + tok];
        #pragma unroll
        for (int g = 0; g < 4; ++g) {
            float4 w4 = *(const float4*)(wt + c * 64 + og * 16 + g * 4);
            acc[g*4+0] = fmaf(zv, w4.x, acc[g*4+0]);
            acc[g*4+1] = fmaf(zv, w4.y, acc[g*4+1]);
            acc[g*4+2] = fmaf(zv, w4.z, acc[g*4+2]);
            acc[g*4+3] = fmaf(zv, w4.w, acc[g*4+3]);
        }
    }
    #pragma unroll
    for (int j = 0; j < 16; ++j) acc[j] = 32.f * (acc[j] + bls[og * 16 + j]);

    uint uh[8], ul[8];
    #pragma unroll
    for (int j = 0; j < 8; ++j) {
        float v0 = acc[2*j], v1 = acc[2*j+1];
        u16 h0 = f2bf(v0), h1 = f2bf(v1);
        u16 l0 = f2bf(v0 - bf2f(h0)), l1 = f2bf(v1 - bf2f(h1));
        uh[j] = (uint)h0 | ((uint)h1 << 16);
        ul[j] = (uint)l0 | ((uint)l1 << 16);
    }
    uint4* zh = (uint4*)(zq + (size_t)n * 128 + og * 16);
    uint4* zl = (uint4*)(zq + (size_t)n * 128 + 64 + og * 16);
    zh[0] = *(uint4*)&uh[0]; zh[1] = *(uint4*)&uh[4];
    zl[0] = *(uint4*)&ul[0]; zl[1] = *(uint4*)&ul[4];
}

// ---------------------------------------------------------------------------
// dist: UNCHANGED from R8/R10 (split-bf16 MFMA + fixed-point u32 top-2).
// ---------------------------------------------------------------------------
__global__ __launch_bounds__(256, 4) void dist_kernel(
    const u16* __restrict__ zq, const u16* __restrict__ embq,
    const float* __restrict__ eebs, uint* __restrict__ halfbb,
    uint* __restrict__ halfss)
{
    __shared__ __attribute__((aligned(16))) char smem[32768];
    __shared__ uint gbk[128];

    const int t    = threadIdx.x;
    const int w    = t >> 6;
    const int l    = t & 63;
    const int col  = l & 31;
    const int half = l >> 5;
    const int tok0 = blockIdx.x * 128;
    const int y    = blockIdx.y;
    const int kbase = y * KCOV;

    bf16x8 ah[4], al[4];
    {
        const u16* zrow = zq + (size_t)(tok0 + w * 32 + col) * 128;
        #pragma unroll
        for (int s = 0; s < 4; ++s) {
            ah[s] = *(const bf16x8*)(zrow + s*16 + half*8);
            al[s] = *(const bf16x8*)(zrow + 64 + s*16 + half*8);
        }
    }

    const int sw = col & 7;
    int boh[4][2], bol[4][2];
    #pragma unroll
    for (int s = 0; s < 4; ++s)
        #pragma unroll
        for (int ct = 0; ct < 2; ++ct) {
            const int nl = ct * 32 + col;
            boh[s][ct] = nl * 256 + (((s*2 + half) ^ sw) << 4);
            bol[s][ct] = nl * 256 + (((8 + s*2 + half) ^ sw) << 4);
        }

    uint bb[16], ss[16];
    #pragma unroll
    for (int r = 0; r < 16; ++r) { bb[r] = 0xFFFFFFFFu; ss[r] = 0xFFFFFFFFu; }

    float e0 = eebs[kbase + col];
    float e1 = eebs[kbase + 32 + col];

    {
        const char* g = (const char*)embq + (size_t)kbase * 256;
        #pragma unroll
        for (int i = 0; i < 4; ++i) {
            int off = i * 4096 + t * 16;
            __builtin_amdgcn_global_load_lds(
                (const __attribute__((address_space(1))) void*)(g + off),
                (__attribute__((address_space(3))) void*)(smem + off), 16, 0, 0);
        }
    }

    for (int kt = 0; kt < NCHUNK; ++kt) {
        __syncthreads();
        if (kt + 1 < NCHUNK) {
            const char* g = (const char*)embq + (size_t)kbase * 256 + (size_t)(kt + 1) * 16384;
            char* ld = smem + ((kt + 1) & 1) * 16384;
            #pragma unroll
            for (int i = 0; i < 4; ++i) {
                int off = i * 4096 + t * 16;
                __builtin_amdgcn_global_load_lds(
                    (const __attribute__((address_space(1))) void*)(g + off),
                    (__attribute__((address_space(3))) void*)(ld + off), 16, 0, 0);
            }
        }
        const char* buf = smem + (kt & 1) * 16384;

        float e0n = 0.f, e1n = 0.f;
        if (kt + 1 < NCHUNK) {
            e0n = eebs[kbase + (kt+1)*64 + col];
            e1n = eebs[kbase + (kt+1)*64 + 32 + col];
        }

        f32x16 a0, a1;
        #pragma unroll
        for (int r = 0; r < 16; ++r) { a0[r] = e0; a1[r] = e1; }

        #pragma unroll
        for (int s = 0; s < 4; ++s) {
            bf16x8 bh0 = *(const bf16x8*)(buf + boh[s][0]);
            bf16x8 bh1 = *(const bf16x8*)(buf + boh[s][1]);
            bf16x8 bl0 = *(const bf16x8*)(buf + bol[s][0]);
            bf16x8 bl1 = *(const bf16x8*)(buf + bol[s][1]);
            a0 = __builtin_amdgcn_mfma_f32_32x32x16_bf16(ah[s], bh0, a0, 0, 0, 0);
            a1 = __builtin_amdgcn_mfma_f32_32x32x16_bf16(ah[s], bh1, a1, 0, 0, 0);
            a0 = __builtin_amdgcn_mfma_f32_32x32x16_bf16(ah[s], bl0, a0, 0, 0, 0);
            a1 = __builtin_amdgcn_mfma_f32_32x32x16_bf16(ah[s], bl1, a1, 0, 0, 0);
            a0 = __builtin_amdgcn_mfma_f32_32x32x16_bf16(al[s], bh0, a0, 0, 0, 0);
            a1 = __builtin_amdgcn_mfma_f32_32x32x16_bf16(al[s], bh1, a1, 0, 0, 0);
        }

        const uint i0 = (uint)(kt * 64 + col);
        const uint i1 = i0 + 32;
        #pragma unroll
        for (int r = 0; r < 16; ++r) {
            const uint p0 = (((uint)a0[r]) << 10) + i0;
            const uint p1 = (((uint)a1[r]) << 10) + i1;
            ss[r] = umin2(ss[r], umed3(bb[r], p0, p1));
            bb[r] = umin2(umin2(bb[r], p0), p1);
        }
        e0 = e0n; e1 = e1n;
    }

    __syncthreads();
    uint* keyt = (uint*)smem;    // [128 tokens][32 slots] u32 = 16 KB
    #pragma unroll
    for (int r = 0; r < 16; ++r) {
        const int tl = w*32 + (r & 3) + 8*(r >> 2) + 4*half;
        keyt[tl * 32 + col] = bb[r];
    }
    __syncthreads();
    if (t < 128) {
        uint gb = keyt[t * 32 + (t & 31)];
        #pragma unroll 4
        for (int j = 1; j < 32; ++j)
            gb = umin2(gb, keyt[t * 32 + ((j + t) & 31)]);
        gbk[t] = gb;
    }
    __syncthreads();
    #pragma unroll
    for (int r = 0; r < 16; ++r) {
        const int tl = w*32 + (r & 3) + 8*(r >> 2) + 4*half;
        const uint mykey = bb[r];
        keyt[tl * 32 + col] = (mykey == gbk[tl]) ? ss[r] : mykey;
    }
    __syncthreads();
    if (t < 128) {
        uint sv = keyt[t * 32 + (t & 31)];
        #pragma unroll 4
        for (int j = 1; j < 32; ++j)
            sv = umin2(sv, keyt[t * 32 + ((j + t) & 31)]);
        halfbb[(size_t)y * NTOK + tok0 + t] = gbk[t];
        halfss[(size_t)y * NTOK + tok0 + t] = sv;
    }
}

// ---------------------------------------------------------------------------
// merge: R8/R10 proven. Combine YSPLIT partitions; flag near-ties.
// ---------------------------------------------------------------------------
__global__ __launch_bounds__(256) void merge_kernel(
    const uint* __restrict__ halfbb, const uint* __restrict__ halfss,
    uint* __restrict__ bestidx, u64* __restrict__ bestkeyB,
    int* __restrict__ flagcnt, int* __restrict__ flaglist)
{
    const int n = blockIdx.x * 256 + threadIdx.x;
    uint m1 = 0xFFFFFFFFu, m2 = 0xFFFFFFFFu, smin = 0xFFFFFFFFu;
    int ywin = 0;
    #pragma unroll
    for (int y = 0; y < YSPLIT; ++y) {
        const uint kb = halfbb[(size_t)y * NTOK + n];
        if (kb < m1) { m2 = m1; m1 = kb; ywin = y; }
        else if (kb < m2) m2 = kb;
        smin = umin2(smin, halfss[(size_t)y * NTOK + n]);
    }
    const uint bv_u = m1 >> 10;
    const uint sv_u = umin2(m2, smin) >> 10;
    const float gap = (float)(sv_u - bv_u) * 9.765625e-4f;   // /1024
    const bool flag = (gap < MARGIN) | (bv_u < (128u << 10));
    bestidx[n]  = flag ? 0xFFFFFFFFu : (uint)(ywin * 1024) + (m1 & 1023u);
    bestkeyB[n] = ~0ull;
    if (flag) {
        int pos = atomicAdd(flagcnt, 1);
        flaglist[pos] = n;
    }
}

// ---------------------------------------------------------------------------
// cleanup: R8/R10 proven. Exact fp32 rescan, 32 slices/token, 2048 blocks.
// ---------------------------------------------------------------------------
__global__ __launch_bounds__(256) void cleanup_kernel(
    const u16* __restrict__ zq, const float* __restrict__ emb,
    const float* __restrict__ ee, const int* __restrict__ flagcnt,
    const int* __restrict__ flaglist, u64* __restrict__ bestkeyB)
{
    __shared__ __attribute__((aligned(16))) float zf[64];
    __shared__ u64 smin;
    const int cnt = *flagcnt;
    const int t = threadIdx.x;

    for (int job = blockIdx.x; job < cnt * 32; job += 2048) {
        const int fi    = job >> 5;
        const int slice = job & 31;
        const int tok   = flaglist[fi];
        if (t == 0) smin = ~0ull;
        if (t < 64) {
            const u16* zr = zq + (size_t)tok * 128;
            zf[t] = (bf2f(zr[t]) + bf2f(zr[64 + t])) * 0.03125f;  // zq = 32*ze
        }
        __syncthreads();

        const int k = slice * 256 + t;
        const float4* er = (const float4*)(emb + (size_t)k * 64);
        float d = 0.f;
        #pragma unroll
        for (int jj = 0; jj < 16; ++jj) {
            float4 e = er[jj];
            float4 zv = *(const float4*)&zf[4*jj];
            d = fmaf(e.x, zv.x, fmaf(e.y, zv.y, fmaf(e.z, zv.z, fmaf(e.w, zv.w, d))));
        }
        float dd = fmaf(-2.f, d, ee[k]);
        u64 key = ((u64)fsort(dd) << 32) | (uint)k;
        #pragma unroll
        for (int off = 32; off > 0; off >>= 1) {
            u64 o = __shfl_down(key, off, 64);
            key = (o < key) ? o : key;
        }
        if ((t & 63) == 0) atomicMin(&smin, key);
        __syncthreads();
        if (t == 0) atomicMin(&bestkeyB[tok], smin);
        __syncthreads();
    }
}

// ---------------------------------------------------------------------------
// finish: near-pure data movement. 512 blocks x 64 tokens.
// Resolve idx -> stage embWb[idx] rows into LDS (transpose) -> coalesced
// channel-major stores. Loss from emb[idx] + zq directly (no conv compute:
// embWb already holds emb @ post_w^T + post_b).
// ---------------------------------------------------------------------------
__global__ __launch_bounds__(256) void finish_kernel(
    const float* __restrict__ emb, const float* __restrict__ embWb,
    const uint* __restrict__ bestidx, const u64* __restrict__ bestkeyB,
    const u16* __restrict__ zq, float* __restrict__ out,
    float* __restrict__ loss_out)
{
    __shared__ __attribute__((aligned(16))) float ot[64 * 64];  // ot[ch][tok]
    __shared__ int idxs[64];
    __shared__ float red[4];
    const int t = threadIdx.x;
    const int tok0 = blockIdx.x * 64;
    const int b    = tok0 >> 12;
    const int hw0  = tok0 & 4095;

    if (t < 64) {
        const uint raw = bestidx[tok0 + t];
        idxs[t] = (raw == 0xFFFFFFFFu) ? (int)(bestkeyB[tok0 + t] & 0xFFFFFFFFull)
                                       : (int)raw;
    }
    __syncthreads();

    const int tok = t >> 2;
    const int og  = t & 3;
    const int n   = tok0 + tok;
    const int idx = idxs[tok];

    // stage output rows (transpose to channel-major for coalesced stores)
    {
        const float4* orow = (const float4*)(embWb + (size_t)idx * 64 + og * 16);
        #pragma unroll
        for (int p = 0; p < 4; ++p) {
            const int c0 = og * 16 + p * 4;
            float4 v = orow[p];
            ot[(c0+0) * 64 + tok] = v.x;
            ot[(c0+1) * 64 + tok] = v.y;
            ot[(c0+2) * 64 + tok] = v.z;
            ot[(c0+3) * 64 + tok] = v.w;
        }
    }

    // loss: q = emb[idx] chunk (exact fp32), ze from zq hi/lo * 1/32
    float lsum = 0.f;
    {
        const float4* qr = (const float4*)(emb + (size_t)idx * 64 + og * 16);
        const uint4* zh = (const uint4*)(zq + (size_t)n * 128 + og * 16);
        const uint4* zl = (const uint4*)(zq + (size_t)n * 128 + 64 + og * 16);
        #pragma unroll
        for (int h = 0; h < 2; ++h) {
            uint4 uh = zh[h], ul = zl[h];
            float4 q0 = qr[h*2], q1 = qr[h*2+1];
            const uint uhv[4] = {uh.x, uh.y, uh.z, uh.w};
            const uint ulv[4] = {ul.x, ul.y, ul.z, ul.w};
            const float qv[8] = {q0.x, q0.y, q0.z, q0.w, q1.x, q1.y, q1.z, q1.w};
            #pragma unroll
            for (int p = 0; p < 4; ++p) {
                float z0 = (bf2f((u16)(uhv[p] & 0xFFFF)) + bf2f((u16)(ulv[p] & 0xFFFF))) * 0.03125f;
                float z1 = (bf2f((u16)(uhv[p] >> 16))    + bf2f((u16)(ulv[p] >> 16)))    * 0.03125f;
                float d0 = z0 - qv[2*p];
                float d1 = z1 - qv[2*p+1];
                lsum += d0 * d0 + d1 * d1;
            }
        }
    }
    __syncthreads();

    // coalesced stores: wave w -> channels w*16..+15, lane = token
    {
        const int w    = t >> 6;
        const int lane = t & 63;
        float* op = out + (size_t)b * (64 * HW) + hw0 + lane;
        #pragma unroll
        for (int j = 0; j < 16; ++j)
            op[(size_t)(w * 16 + j) * HW] = ot[(w * 16 + j) * 64 + lane];
    }

    #pragma unroll
    for (int off = 32; off > 0; off >>= 1) lsum += __shfl_down(lsum, off, 64);
    if ((t & 63) == 0) red[t >> 6] = lsum;
    __syncthreads();
    if (t == 0) {
        const float tot = red[0] + red[1] + red[2] + red[3];
        atomicAdd(loss_out, tot * (1.25f / 2097152.f));   // 1.25/(NTOK*64)
    }
}

// ---------------------------------------------------------------------------
extern "C" void kernel_launch(void* const* d_in, const int* in_sizes, int n_in,
                              void* d_out, int out_size, void* d_ws, size_t ws_size,
                              hipStream_t stream)
{
    const float* z      = (const float*)d_in[0];
    const float* pre_w  = (const float*)d_in[1];
    const float* pre_b  = (const float*)d_in[2];
    const float* emb    = (const float*)d_in[3];
    const float* post_w = (const float*)d_in[4];
    const float* post_b = (const float*)d_in[5];
    float* outp = (float*)d_out;
    float* loss_out = outp + (size_t)NTOK * 64;

    u16*   zq       = (u16*)d_ws;                          // 8 MB
    float* ee       = (float*)(zq + (size_t)NTOK * 128);   // 32 KB
    float* eebs     = ee + KCB;                            // 32 KB
    u16*   embq     = (u16*)(eebs + KCB);                  // 2 MB
    u64*   bestkeyB = (u64*)(embq + (size_t)KCB * 128);    // 256 KB (8B-aligned)
    uint*  bestidx  = (uint*)(bestkeyB + NTOK);            // 128 KB
    int*   flagcnt  = (int*)(bestidx + NTOK);              // 4 B
    int*   flaglist = flagcnt + 1;                         // 128 KB
    uint*  halfbb   = (uint*)(flaglist + NTOK);            // 1 MB
    uint*  halfss   = halfbb + (size_t)YSPLIT * NTOK;      // 1 MB
    float* embWb    = (float*)(halfss + (size_t)YSPLIT * NTOK); // 2 MB

    prep_kernel<<<896, 256, 0, stream>>>(z, pre_w, pre_b, emb, post_w, post_b,
                                         zq, embq, ee, eebs, embWb, loss_out, flagcnt);
    dist_kernel<<<dim3(NTOK / 128, YSPLIT), 256, 0, stream>>>(zq, embq, eebs, halfbb, halfss);
    merge_kernel<<<NTOK / 256, 256, 0, stream>>>(halfbb, halfss, bestidx, bestkeyB,
                                                 flagcnt, flaglist);
    cleanup_kernel<<<2048, 256, 0, stream>>>(zq, emb, ee, flagcnt, flaglist, bestkeyB);
    finish_kernel<<<NTOK / 64, 256, 0, stream>>>(emb, embWb, bestidx, bestkeyB, zq,
                                                 outp, loss_out);
}